// Round 1
// baseline (370.538 us; speedup 1.0000x reference)
//
#include <hip/hip_runtime.h>
#include <stdint.h>

typedef unsigned short u16;
typedef unsigned int u32;
typedef __bf16 bf16_t;
typedef __bf16 bf16x4 __attribute__((ext_vector_type(4)));
typedef __bf16 bf16x8 __attribute__((ext_vector_type(8)));
typedef float f32x4 __attribute__((ext_vector_type(4)));
typedef float f32x16 __attribute__((ext_vector_type(16)));

#define LOG2E 1.4426950408889634f
#define MFMA32(a, b, c) __builtin_amdgcn_mfma_f32_32x32x16_bf16(a, b, c, 0, 0, 0)

__device__ __forceinline__ u16 f2bf(float f) {
    union { float f; unsigned int u; } v; v.f = f;
    unsigned int r = v.u + 0x7fffu + ((v.u >> 16) & 1u);
    return (u16)(r >> 16);
}

__device__ __forceinline__ bf16x8 ld8f_bf(const float* __restrict__ p) {
    float4 a = *reinterpret_cast<const float4*>(p);
    float4 b = *reinterpret_cast<const float4*>(p + 4);
    bf16x8 r;
    r[0] = (bf16_t)a.x; r[1] = (bf16_t)a.y; r[2] = (bf16_t)a.z; r[3] = (bf16_t)a.w;
    r[4] = (bf16_t)b.x; r[5] = (bf16_t)b.y; r[6] = (bf16_t)b.z; r[7] = (bf16_t)b.w;
    return r;
}

__device__ __forceinline__ u32 cvt_pk_bf16(float a, float b) {
    u32 r;
    asm("v_cvt_pk_bf16_f32 %0, %1, %2" : "=v"(r) : "v"(a), "v"(b));
    return r;
}

__device__ __forceinline__ void plane32_swap(u32& a, u32& b) {
    asm("v_permlane32_swap_b32 %0, %1" : "+v"(a), "+v"(b));
}

// Build PV B-operand fragment (16 keys) from 8 consecutive QK C-regs.
// C layout: key_rel = (r&3) + 8*(r>>2) + 4*hi, q = lane&31.
// B layout needed: key_rel = 8*hi + j (j=0..7), q = lane&31.
__device__ __forceinline__ bf16x8 pack8(const float* p) {
    u32 c0 = cvt_pk_bf16(p[0], p[1]);   // keys {4hi+0, 4hi+1}
    u32 c1 = cvt_pk_bf16(p[2], p[3]);   // keys {4hi+2, 4hi+3}
    u32 c2 = cvt_pk_bf16(p[4], p[5]);   // keys {8+4hi, 8+4hi+1}
    u32 c3 = cvt_pk_bf16(p[6], p[7]);   // keys {8+4hi+2, 8+4hi+3}
    plane32_swap(c0, c2);               // c0 -> w0 {0,1}|{8,9}, c2 -> w2 {4,5}|{12,13}
    plane32_swap(c1, c3);               // c1 -> w1 {2,3}|{10,11}, c3 -> w3 {6,7}|{14,15}
    union { u32 u[4]; bf16x8 v; } f;
    f.u[0] = c0; f.u[1] = c1; f.u[2] = c2; f.u[3] = c3;
    return f.v;
}

// ---------------------------------------------------------------------------
// Kernel 1: x[B,C,N] fp32 -> xT[B,N,C] bf16  (xT staged in d_out's 32 MiB)
// ---------------------------------------------------------------------------
__global__ __launch_bounds__(256) void k_transpose(const float* __restrict__ x,
                                                   u16* __restrict__ xT) {
    __shared__ u16 tile[64][68];
    int blk = blockIdx.x;
    int b = blk >> 8;
    int r = blk & 255;
    int c0 = (r & 3) * 64;
    int n0 = (r >> 2) * 64;
    const float* xb = x + (size_t)b * 256 * 4096;
    u16* xTb = xT + (size_t)b * 4096 * 256;
    int t = threadIdx.x;
    int lc = t >> 4;
    int l4 = (t & 15) * 4;
    #pragma unroll
    for (int p = 0; p < 4; ++p) {
        int c = lc + p * 16;
        float4 v = *reinterpret_cast<const float4*>(xb + (size_t)(c0 + c) * 4096 + n0 + l4);
        tile[c][l4 + 0] = f2bf(v.x); tile[c][l4 + 1] = f2bf(v.y);
        tile[c][l4 + 2] = f2bf(v.z); tile[c][l4 + 3] = f2bf(v.w);
    }
    __syncthreads();
    #pragma unroll
    for (int p = 0; p < 4; ++p) {
        int n = lc + p * 16;
        ushort4 v;
        v.x = tile[l4 + 0][n]; v.y = tile[l4 + 1][n];
        v.z = tile[l4 + 2][n]; v.w = tile[l4 + 3][n];
        *reinterpret_cast<ushort4*>(xTb + (size_t)(n0 + n) * 256 + c0 + l4) = v;
    }
}

// ---------------------------------------------------------------------------
// Kernel 2: fused q/k/v projection (unchanged structure; q now pre-scaled by
// LOG2E so k_flash can use exp2 directly).
// ---------------------------------------------------------------------------
__global__ __launch_bounds__(256, 2) void k_proj(
    const u16* __restrict__ xT,
    const float* __restrict__ Wq, const float* __restrict__ bq,
    const float* __restrict__ Wk, const float* __restrict__ bk,
    const float* __restrict__ Wv, const float* __restrict__ bv,
    u16* __restrict__ qt, u16* __restrict__ kt, u16* __restrict__ vn) {
    __shared__ u16 Xs[64 * 256];    // [n][c] granules swizzled by n&7
    __shared__ u16 Ws[64 * 256];    // rows 0-31 Wq, 32-63 Wk; swizzle row&7
    __shared__ u16 Wvs[256 * 32];   // [co][c-slice] granules swizzled by co&3
    int blk = blockIdx.x;
    int b = blk & 7;
    int n0 = (blk >> 3) * 64;
    int t = threadIdx.x;
    int w = t >> 6;
    int lane = t & 63;
    int lo = lane & 15;
    int q = lane >> 4;
    const u16* xTb = xT + (size_t)b * 4096 * 256;

    #pragma unroll
    for (int p = 0; p < 8; ++p) {
        int G = p * 256 + t;
        int n = G >> 5, g = G & 31;
        bf16x8 v = *reinterpret_cast<const bf16x8*>(
            xTb + (size_t)(n0 + n) * 256 + g * 8);
        *reinterpret_cast<bf16x8*>(&Xs[(n * 32 + (g ^ (n & 7))) * 8]) = v;
        const float* src = (n < 32) ? (Wq + (size_t)n * 256 + g * 8)
                                    : (Wk + (size_t)(n - 32) * 256 + g * 8);
        *reinterpret_cast<bf16x8*>(&Ws[(n * 32 + (g ^ (n & 7))) * 8]) = ld8f_bf(src);
    }

    f32x4 accqk[4] = {};
    f32x4 accv[16];
    #pragma unroll
    for (int i = 0; i < 16; ++i) accv[i] = f32x4{0.f, 0.f, 0.f, 0.f};

    int rowA = w * 16 + lo;
    int cw = w * 64;
    for (int c0 = 0; c0 < 256; c0 += 32) {
        __syncthreads();
        #pragma unroll
        for (int p = 0; p < 4; ++p) {
            int G = p * 256 + t;
            int co = G >> 2, g2 = G & 3;
            *reinterpret_cast<bf16x8*>(&Wvs[(co * 4 + (g2 ^ (co & 3))) * 8]) =
                ld8f_bf(Wv + (size_t)co * 256 + c0 + g2 * 8);
        }
        __syncthreads();

        int K = c0 >> 3;
        bf16x8 a = *reinterpret_cast<const bf16x8*>(
            &Xs[(rowA * 32 + ((K + q) ^ (lo & 7))) * 8]);
        #pragma unroll
        for (int ot = 0; ot < 4; ++ot) {
            bf16x8 bb = *reinterpret_cast<const bf16x8*>(
                &Ws[((ot * 16 + lo) * 32 + ((K + q) ^ (lo & 7))) * 8]);
            accqk[ot] = __builtin_amdgcn_mfma_f32_16x16x32_bf16(a, bb, accqk[ot], 0, 0, 0);
        }
        bf16x8 xbf[4];
        #pragma unroll
        for (int nt = 0; nt < 4; ++nt)
            xbf[nt] = *reinterpret_cast<const bf16x8*>(
                &Xs[((nt * 16 + lo) * 32 + ((K + q) ^ (lo & 7))) * 8]);
        #pragma unroll
        for (int ct = 0; ct < 4; ++ct) {
            int co = cw + ct * 16 + lo;
            bf16x8 av = *reinterpret_cast<const bf16x8*>(
                &Wvs[(co * 4 + (q ^ (co & 3))) * 8]);
            #pragma unroll
            for (int nt = 0; nt < 4; ++nt)
                accv[ct * 4 + nt] = __builtin_amdgcn_mfma_f32_16x16x32_bf16(
                    av, xbf[nt], accv[ct * 4 + nt], 0, 0, 0);
        }
    }
    #pragma unroll
    for (int ot = 0; ot < 4; ++ot) {
        float bias = (ot < 2) ? bq[ot * 16 + lo] : bk[(ot - 2) * 16 + lo];
        #pragma unroll
        for (int r = 0; r < 4; ++r) {
            int n = n0 + w * 16 + q * 4 + r;
            float val = accqk[ot][r] + bias;
            if (ot < 2) qt[((size_t)b * 4096 + n) * 32 + ot * 16 + lo] = f2bf(val * LOG2E);
            else        kt[((size_t)b * 4096 + n) * 32 + (ot - 2) * 16 + lo] = f2bf(val);
        }
    }
    #pragma unroll
    for (int ct = 0; ct < 4; ++ct) {
        #pragma unroll
        for (int nt = 0; nt < 4; ++nt) {
            #pragma unroll
            for (int r = 0; r < 4; ++r) {
                int co = cw + ct * 16 + q * 4 + r;
                float val = accv[ct * 4 + nt][r] + bv[co];
                vn[((size_t)b * 256 + co) * 4096 + n0 + nt * 16 + lo] = f2bf(val);
            }
        }
    }
}

// ---------------------------------------------------------------------------
// Kernel 3 (v5): barrier-free flash attention, 32x32 MFMA, E in registers.
// Block = 128 q-rows x 128 ch; wave w owns q-rows [m0+32w, m0+32w+32) and
// ALL 128 block channels. QK C-regs -> exp2 -> cvt_pk + permlane32_swap ->
// PV B-operand, entirely in registers. Zero LDS, zero __syncthreads.
// ---------------------------------------------------------------------------
__global__ __launch_bounds__(256, 2) void k_flash(
    const u16* __restrict__ qt, const u16* __restrict__ kt,
    const u16* __restrict__ vn, const float* __restrict__ x,
    const float* __restrict__ gamma, float* __restrict__ out) {
    int blk = blockIdx.x;
    int b = blk & 7;
    int rest = blk >> 3;
    int m0 = (rest & 31) * 128;
    int ch0 = (rest >> 5) * 128;
    int t = threadIdx.x;
    int w = t >> 6;
    int lane = t & 63;
    int la = lane & 31;
    int hi = lane >> 5;

    const u16* qtb = qt + (size_t)b * 4096 * 32;
    const u16* ktb = kt + (size_t)b * 4096 * 32;
    const u16* vbp = vn + (size_t)b * 256 * 4096;

    int qw0 = m0 + w * 32;
    // Q as B-operand: col = la (q-row), k = 16*h + 8*hi + j
    bf16x8 qf0 = *reinterpret_cast<const bf16x8*>(qtb + (size_t)(qw0 + la) * 32 + hi * 8);
    bf16x8 qf1 = *reinterpret_cast<const bf16x8*>(qtb + (size_t)(qw0 + la) * 32 + 16 + hi * 8);

    f32x16 O0 = {}, O1 = {}, O2 = {}, O3 = {};
    const f32x16 z16 = {};
    float lsum = 0.f;

    // K as A-operand: row = la (key), k = 16*h + 8*hi + j
    const u16* kp  = ktb + (size_t)la * 32 + hi * 8;
    // V as A-operand: row = la (ch), k = 8*hi + j (keys)
    const u16* vp0 = vbp + (size_t)(ch0 +  0 + la) * 4096 + hi * 8;
    const u16* vp1 = vbp + (size_t)(ch0 + 32 + la) * 4096 + hi * 8;
    const u16* vp2 = vbp + (size_t)(ch0 + 64 + la) * 4096 + hi * 8;
    const u16* vp3 = vbp + (size_t)(ch0 + 96 + la) * 4096 + hi * 8;

    bf16x8 kf0 = *reinterpret_cast<const bf16x8*>(kp);
    bf16x8 kf1 = *reinterpret_cast<const bf16x8*>(kp + 16);
    bf16x8 kf2 = *reinterpret_cast<const bf16x8*>(kp + 1024);
    bf16x8 kf3 = *reinterpret_cast<const bf16x8*>(kp + 1040);

    for (int s = 0; s < 64; ++s) {
        int n0 = s * 64;
        int nn = (s < 63) ? (n0 + 64) : 0;
        const u16* kpn = kp + (size_t)nn * 32;
        bf16x8 kn0 = *reinterpret_cast<const bf16x8*>(kpn);
        bf16x8 kn1 = *reinterpret_cast<const bf16x8*>(kpn + 16);
        bf16x8 kn2 = *reinterpret_cast<const bf16x8*>(kpn + 1024);
        bf16x8 kn3 = *reinterpret_cast<const bf16x8*>(kpn + 1040);

        // ---- QK tile0 (keys n0..n0+31): E[key][q], q pre-scaled by LOG2E ----
        f32x16 S0 = MFMA32(kf0, qf0, z16);
        S0 = MFMA32(kf1, qf1, S0);

        // ---- V loads for tile0 (chunks k0: +0, k1: +16) ----
        bf16x8 va0 = *reinterpret_cast<const bf16x8*>(vp0 + n0);
        bf16x8 va1 = *reinterpret_cast<const bf16x8*>(vp1 + n0);
        bf16x8 va2 = *reinterpret_cast<const bf16x8*>(vp2 + n0);
        bf16x8 va3 = *reinterpret_cast<const bf16x8*>(vp3 + n0);
        bf16x8 vb0 = *reinterpret_cast<const bf16x8*>(vp0 + n0 + 16);
        bf16x8 vb1 = *reinterpret_cast<const bf16x8*>(vp1 + n0 + 16);
        bf16x8 vb2 = *reinterpret_cast<const bf16x8*>(vp2 + n0 + 16);
        bf16x8 vb3 = *reinterpret_cast<const bf16x8*>(vp3 + n0 + 16);

        // ---- QK tile1 (keys n0+32..n0+63) ----
        f32x16 S1 = MFMA32(kf2, qf0, z16);
        S1 = MFMA32(kf3, qf1, S1);

        // ---- exp + pack tile0 ----
        float p0[16];
        #pragma unroll
        for (int i = 0; i < 16; ++i) {
            p0[i] = __builtin_amdgcn_exp2f(S0[i]);
            lsum += p0[i];
        }
        bf16x8 fA = pack8(p0);
        bf16x8 fB = pack8(p0 + 8);

        // ---- V loads for tile1 ----
        bf16x8 vc0 = *reinterpret_cast<const bf16x8*>(vp0 + n0 + 32);
        bf16x8 vc1 = *reinterpret_cast<const bf16x8*>(vp1 + n0 + 32);
        bf16x8 vc2 = *reinterpret_cast<const bf16x8*>(vp2 + n0 + 32);
        bf16x8 vc3 = *reinterpret_cast<const bf16x8*>(vp3 + n0 + 32);
        bf16x8 vd0 = *reinterpret_cast<const bf16x8*>(vp0 + n0 + 48);
        bf16x8 vd1 = *reinterpret_cast<const bf16x8*>(vp1 + n0 + 48);
        bf16x8 vd2 = *reinterpret_cast<const bf16x8*>(vp2 + n0 + 48);
        bf16x8 vd3 = *reinterpret_cast<const bf16x8*>(vp3 + n0 + 48);

        // ---- PV tile0: O[ch][q] += V[ch][key] * P[q][key] ----
        O0 = MFMA32(va0, fA, O0);
        O1 = MFMA32(va1, fA, O1);
        O2 = MFMA32(va2, fA, O2);
        O3 = MFMA32(va3, fA, O3);
        O0 = MFMA32(vb0, fB, O0);
        O1 = MFMA32(vb1, fB, O1);
        O2 = MFMA32(vb2, fB, O2);
        O3 = MFMA32(vb3, fB, O3);

        // ---- exp + pack tile1 ----
        float p1[16];
        #pragma unroll
        for (int i = 0; i < 16; ++i) {
            p1[i] = __builtin_amdgcn_exp2f(S1[i]);
            lsum += p1[i];
        }
        bf16x8 fC = pack8(p1);
        bf16x8 fD = pack8(p1 + 8);

        // ---- PV tile1 ----
        O0 = MFMA32(vc0, fC, O0);
        O1 = MFMA32(vc1, fC, O1);
        O2 = MFMA32(vc2, fC, O2);
        O3 = MFMA32(vc3, fC, O3);
        O0 = MFMA32(vd0, fD, O0);
        O1 = MFMA32(vd1, fD, O1);
        O2 = MFMA32(vd2, fD, O2);
        O3 = MFMA32(vd3, fD, O3);

        kf0 = kn0; kf1 = kn1; kf2 = kn2; kf3 = kn3;
    }

    // row-sum completion: lane hi-halves each hold half the keys for q = la
    lsum += __shfl_xor(lsum, 32, 64);
    float linv = 1.0f / lsum;
    float g = gamma[0];
    const float* xb = x + (size_t)b * 256 * 4096;
    float* ob = out + (size_t)b * 256 * 4096;
    int m = m0 + w * 32 + la;
    #pragma unroll
    for (int r = 0; r < 16; ++r) {
        int crow = (r & 3) + 8 * (r >> 2) + 4 * hi;
        size_t i0 = (size_t)(ch0 + crow) * 4096 + m;
        ob[i0]             = g * (O0[r] * linv) + xb[i0];
        ob[i0 + 32 * 4096] = g * (O1[r] * linv) + xb[i0 + 32 * 4096];
        ob[i0 + 64 * 4096] = g * (O2[r] * linv) + xb[i0 + 64 * 4096];
        ob[i0 + 96 * 4096] = g * (O3[r] * linv) + xb[i0 + 96 * 4096];
    }
}

// ---------------------------------------------------------------------------
// fp32 I/O. Internal bf16. Workspace: qt 2 + kt 2 + vn 16 = 20 MiB.
// xT (bf16, 16 MiB) staged inside fp32 d_out (32 MiB); dead before k_flash.
// ---------------------------------------------------------------------------
extern "C" void kernel_launch(void* const* d_in, const int* in_sizes, int n_in,
                              void* d_out, int out_size, void* d_ws, size_t ws_size,
                              hipStream_t stream) {
    const float* x     = (const float*)d_in[0];
    const float* Wq    = (const float*)d_in[1];
    const float* bq    = (const float*)d_in[2];
    const float* Wk    = (const float*)d_in[3];
    const float* bk    = (const float*)d_in[4];
    const float* Wv    = (const float*)d_in[5];
    const float* bv    = (const float*)d_in[6];
    const float* gamma = (const float*)d_in[7];
    float* out = (float*)d_out;

    char* ws = (char*)d_ws;
    u16* xT = (u16*)d_out;                        // 16 MiB bf16 scratch in fp32 d_out
    u16* qt = (u16*)ws;                           //  2 MiB [B,N,32]
    u16* kt = (u16*)(ws + 2097152);               //  2 MiB [B,N,32]
    u16* vn = (u16*)(ws + 2 * 2097152);           // 16 MiB [B,C,N]

    k_transpose<<<2048, 256, 0, stream>>>(x, xT);
    k_proj<<<512, 256, 0, stream>>>(xT, Wq, bq, Wk, bk, Wv, bv, qt, kt, vn);
    k_flash<<<512, 256, 0, stream>>>(qt, kt, vn, x, gamma, out);
}

// Round 3
// 204.353 us; speedup vs baseline: 1.8132x; 1.8132x over previous
//
#include <hip/hip_runtime.h>
#include <stdint.h>

typedef unsigned short u16;
typedef unsigned int u32;
typedef __bf16 bf16_t;
typedef __bf16 bf16x4 __attribute__((ext_vector_type(4)));
typedef __bf16 bf16x8 __attribute__((ext_vector_type(8)));
typedef float f32x4 __attribute__((ext_vector_type(4)));
typedef float f32x16 __attribute__((ext_vector_type(16)));

#define LOG2E 1.4426950408889634f
#define MFMA32(a, b, c) __builtin_amdgcn_mfma_f32_32x32x16_bf16(a, b, c, 0, 0, 0)

__device__ __forceinline__ u16 f2bf(float f) {
    union { float f; unsigned int u; } v; v.f = f;
    unsigned int r = v.u + 0x7fffu + ((v.u >> 16) & 1u);
    return (u16)(r >> 16);
}

__device__ __forceinline__ bf16x8 ld8f_bf(const float* __restrict__ p) {
    float4 a = *reinterpret_cast<const float4*>(p);
    float4 b = *reinterpret_cast<const float4*>(p + 4);
    bf16x8 r;
    r[0] = (bf16_t)a.x; r[1] = (bf16_t)a.y; r[2] = (bf16_t)a.z; r[3] = (bf16_t)a.w;
    r[4] = (bf16_t)b.x; r[5] = (bf16_t)b.y; r[6] = (bf16_t)b.z; r[7] = (bf16_t)b.w;
    return r;
}

__device__ __forceinline__ u32 cvt_pk_bf16(float a, float b) {
    u32 r;
    asm("v_cvt_pk_bf16_f32 %0, %1, %2" : "=v"(r) : "v"(a), "v"(b));
    return r;
}

__device__ __forceinline__ void plane32_swap(u32& a, u32& b) {
    asm("v_permlane32_swap_b32 %0, %1" : "+v"(a), "+v"(b));
}

// Build PV B-operand fragment (16 keys) from 8 consecutive QK C-regs.
__device__ __forceinline__ bf16x8 pack8(const float* p) {
    u32 c0 = cvt_pk_bf16(p[0], p[1]);
    u32 c1 = cvt_pk_bf16(p[2], p[3]);
    u32 c2 = cvt_pk_bf16(p[4], p[5]);
    u32 c3 = cvt_pk_bf16(p[6], p[7]);
    plane32_swap(c0, c2);
    plane32_swap(c1, c3);
    union { u32 u[4]; bf16x8 v; } f;
    f.u[0] = c0; f.u[1] = c1; f.u[2] = c2; f.u[3] = c3;
    return f.v;
}

// async global->LDS, 16B per lane; LDS dest wave-uniform base + lane*16
__device__ __forceinline__ void g2lds16(const u16* g, u16* l) {
    __builtin_amdgcn_global_load_lds(
        (const __attribute__((address_space(1))) unsigned int*)g,
        (__attribute__((address_space(3))) unsigned int*)l, 16, 0, 0);
}

// ---------------------------------------------------------------------------
// Kernel 1: x[B,C,N] fp32 -> xT[B,N,C] bf16  (xT staged in d_out's 32 MiB)
// ---------------------------------------------------------------------------
__global__ __launch_bounds__(256) void k_transpose(const float* __restrict__ x,
                                                   u16* __restrict__ xT) {
    __shared__ u16 tile[64][68];
    int blk = blockIdx.x;
    int b = blk >> 8;
    int r = blk & 255;
    int c0 = (r & 3) * 64;
    int n0 = (r >> 2) * 64;
    const float* xb = x + (size_t)b * 256 * 4096;
    u16* xTb = xT + (size_t)b * 4096 * 256;
    int t = threadIdx.x;
    int lc = t >> 4;
    int l4 = (t & 15) * 4;
    #pragma unroll
    for (int p = 0; p < 4; ++p) {
        int c = lc + p * 16;
        float4 v = *reinterpret_cast<const float4*>(xb + (size_t)(c0 + c) * 4096 + n0 + l4);
        tile[c][l4 + 0] = f2bf(v.x); tile[c][l4 + 1] = f2bf(v.y);
        tile[c][l4 + 2] = f2bf(v.z); tile[c][l4 + 3] = f2bf(v.w);
    }
    __syncthreads();
    #pragma unroll
    for (int p = 0; p < 4; ++p) {
        int n = lc + p * 16;
        ushort4 v;
        v.x = tile[l4 + 0][n]; v.y = tile[l4 + 1][n];
        v.z = tile[l4 + 2][n]; v.w = tile[l4 + 3][n];
        *reinterpret_cast<ushort4*>(xTb + (size_t)(n0 + n) * 256 + c0 + l4) = v;
    }
}

// ---------------------------------------------------------------------------
// Kernel 2: fused q/k/v projection. q pre-scaled by LOG2E. V written in
// flash-friendly layout vt[b][n>>4][ch][n&15] (contiguous 16-key rows).
// ---------------------------------------------------------------------------
__global__ __launch_bounds__(256, 2) void k_proj(
    const u16* __restrict__ xT,
    const float* __restrict__ Wq, const float* __restrict__ bq,
    const float* __restrict__ Wk, const float* __restrict__ bk,
    const float* __restrict__ Wv, const float* __restrict__ bv,
    u16* __restrict__ qt, u16* __restrict__ kt, u16* __restrict__ vt) {
    __shared__ u16 Xs[64 * 256];
    __shared__ u16 Ws[64 * 256];
    __shared__ u16 Wvs[256 * 32];
    int blk = blockIdx.x;
    int b = blk & 7;
    int n0 = (blk >> 3) * 64;
    int t = threadIdx.x;
    int w = t >> 6;
    int lane = t & 63;
    int lo = lane & 15;
    int q = lane >> 4;
    const u16* xTb = xT + (size_t)b * 4096 * 256;

    #pragma unroll
    for (int p = 0; p < 8; ++p) {
        int G = p * 256 + t;
        int n = G >> 5, g = G & 31;
        bf16x8 v = *reinterpret_cast<const bf16x8*>(
            xTb + (size_t)(n0 + n) * 256 + g * 8);
        *reinterpret_cast<bf16x8*>(&Xs[(n * 32 + (g ^ (n & 7))) * 8]) = v;
        const float* src = (n < 32) ? (Wq + (size_t)n * 256 + g * 8)
                                    : (Wk + (size_t)(n - 32) * 256 + g * 8);
        *reinterpret_cast<bf16x8*>(&Ws[(n * 32 + (g ^ (n & 7))) * 8]) = ld8f_bf(src);
    }

    f32x4 accqk[4] = {};
    f32x4 accv[16];
    #pragma unroll
    for (int i = 0; i < 16; ++i) accv[i] = f32x4{0.f, 0.f, 0.f, 0.f};

    int rowA = w * 16 + lo;
    int cw = w * 64;
    for (int c0 = 0; c0 < 256; c0 += 32) {
        __syncthreads();
        #pragma unroll
        for (int p = 0; p < 4; ++p) {
            int G = p * 256 + t;
            int co = G >> 2, g2 = G & 3;
            *reinterpret_cast<bf16x8*>(&Wvs[(co * 4 + (g2 ^ (co & 3))) * 8]) =
                ld8f_bf(Wv + (size_t)co * 256 + c0 + g2 * 8);
        }
        __syncthreads();

        int K = c0 >> 3;
        bf16x8 a = *reinterpret_cast<const bf16x8*>(
            &Xs[(rowA * 32 + ((K + q) ^ (lo & 7))) * 8]);
        #pragma unroll
        for (int ot = 0; ot < 4; ++ot) {
            bf16x8 bb = *reinterpret_cast<const bf16x8*>(
                &Ws[((ot * 16 + lo) * 32 + ((K + q) ^ (lo & 7))) * 8]);
            accqk[ot] = __builtin_amdgcn_mfma_f32_16x16x32_bf16(a, bb, accqk[ot], 0, 0, 0);
        }
        bf16x8 xbf[4];
        #pragma unroll
        for (int nt = 0; nt < 4; ++nt)
            xbf[nt] = *reinterpret_cast<const bf16x8*>(
                &Xs[((nt * 16 + lo) * 32 + ((K + q) ^ (lo & 7))) * 8]);
        #pragma unroll
        for (int ct = 0; ct < 4; ++ct) {
            int co = cw + ct * 16 + lo;
            bf16x8 av = *reinterpret_cast<const bf16x8*>(
                &Wvs[(co * 4 + (q ^ (co & 3))) * 8]);
            #pragma unroll
            for (int nt = 0; nt < 4; ++nt)
                accv[ct * 4 + nt] = __builtin_amdgcn_mfma_f32_16x16x32_bf16(
                    av, xbf[nt], accv[ct * 4 + nt], 0, 0, 0);
        }
    }
    #pragma unroll
    for (int ot = 0; ot < 4; ++ot) {
        float bias = (ot < 2) ? bq[ot * 16 + lo] : bk[(ot - 2) * 16 + lo];
        #pragma unroll
        for (int r = 0; r < 4; ++r) {
            int n = n0 + w * 16 + q * 4 + r;
            float val = accqk[ot][r] + bias;
            if (ot < 2) qt[((size_t)b * 4096 + n) * 32 + ot * 16 + lo] = f2bf(val * LOG2E);
            else        kt[((size_t)b * 4096 + n) * 32 + (ot - 2) * 16 + lo] = f2bf(val);
        }
    }
    // V epilogue in vt[b][nt][ch][k16] layout: n = n0 + nt*16 + lo -> nt_g, k16=lo
    #pragma unroll
    for (int ct = 0; ct < 4; ++ct) {
        #pragma unroll
        for (int nt = 0; nt < 4; ++nt) {
            int nt_g = (n0 >> 4) + nt;
            #pragma unroll
            for (int r = 0; r < 4; ++r) {
                int co = cw + ct * 16 + q * 4 + r;
                float val = accv[ct * 4 + nt][r] + bv[co];
                vt[(((size_t)b * 256 + nt_g) * 256 + co) * 16 + lo] = f2bf(val);
            }
        }
    }
}

// ---------------------------------------------------------------------------
// Kernel 3 (v6): flash attention, 32x32 MFMA, E in registers, V+K staged in
// LDS (shared by all 4 waves), double-buffered, global_load_lds prefetch.
// LDS chunks = 64 granules x 16B; granule g stored at slot g^(g>>3)
// (involution) via pre-swizzled global source addresses -> 2-way-free reads.
// ---------------------------------------------------------------------------
__global__ __launch_bounds__(256, 2) void k_flash(
    const u16* __restrict__ qt, const u16* __restrict__ kt,
    const u16* __restrict__ vt, const float* __restrict__ x,
    const float* __restrict__ gamma, float* __restrict__ out) {
    __shared__ u16 Vs[2][8192];   // 16 chunks (kc*4+cg) x 512 u16
    __shared__ u16 Ks[2][2048];   // 4 chunks (kt2*2+h) x 512 u16
    int blk = blockIdx.x;
    int b = blk & 7;
    int rest = blk >> 3;
    int m0 = (rest & 31) * 128;
    int ch0 = (rest >> 5) * 128;
    int t = threadIdx.x;
    int w = t >> 6;
    int lane = t & 63;
    int la = lane & 31;
    int hi = lane >> 5;

    const u16* qtb = qt + (size_t)b * 4096 * 32;
    const u16* ktb = kt + (size_t)b * 4096 * 32;
    const u16* vtb = vt + (size_t)b * 256 * 256 * 16;

    int qw0 = m0 + w * 32;
    bf16x8 qf0 = *reinterpret_cast<const bf16x8*>(qtb + (size_t)(qw0 + la) * 32 + hi * 8);
    bf16x8 qf1 = *reinterpret_cast<const bf16x8*>(qtb + (size_t)(qw0 + la) * 32 + 16 + hi * 8);

    int g = la * 2 + hi;
    int gslot8 = (g ^ (g >> 3)) * 8;          // u16 offset of this lane's read slot
    int sg = lane ^ (lane >> 3);              // source granule for staging slot=lane

    // staging pointers for step 0 (wave w stages V kc=w cg=0..3 and K chunk w)
    const u16* vsrc = vtb + ((size_t)w * 256 + ch0) * 16 + sg * 8;
    const u16* ksrc = ktb + (size_t)((w >> 1) * 32 + (sg >> 1)) * 32 + (w & 1) * 16 + (sg & 1) * 8;
    u16* vdstA = &Vs[0][w * 4 * 512];
    u16* kdstA = &Ks[0][w * 512];
    u16* vdstB = &Vs[1][w * 4 * 512];
    u16* kdstB = &Ks[1][w * 512];

    // prologue: stage step 0 into buffer 0
    #pragma unroll
    for (int i = 0; i < 4; ++i) g2lds16(vsrc + i * 512, vdstA + i * 512);
    g2lds16(ksrc, kdstA);
    vsrc += 16384;   // next 4 nt-chunks
    ksrc += 2048;    // next 64 keys

    f32x16 O0 = {}, O1 = {}, O2 = {}, O3 = {};
    const f32x16 z16 = {};
    float lsum = 0.f;
    __syncthreads();

    for (int s = 0; s < 64; ++s) {
        const u16* Vc = Vs[s & 1];
        const u16* Kc = Ks[s & 1];
        // ---- prefetch step s+1 into other buffer ----
        if (s < 63) {
            u16* vd = (s & 1) ? vdstA : vdstB;
            u16* kd = (s & 1) ? kdstA : kdstB;
            #pragma unroll
            for (int i = 0; i < 4; ++i) g2lds16(vsrc + i * 512, vd + i * 512);
            g2lds16(ksrc, kd);
            vsrc += 16384;
            ksrc += 2048;
        }
        // ---- K fragments ----
        bf16x8 kf00 = *reinterpret_cast<const bf16x8*>(Kc + 0 * 512 + gslot8);
        bf16x8 kf01 = *reinterpret_cast<const bf16x8*>(Kc + 1 * 512 + gslot8);
        bf16x8 kf10 = *reinterpret_cast<const bf16x8*>(Kc + 2 * 512 + gslot8);
        bf16x8 kf11 = *reinterpret_cast<const bf16x8*>(Kc + 3 * 512 + gslot8);
        // ---- QK ----
        f32x16 S0 = MFMA32(kf00, qf0, z16);
        S0 = MFMA32(kf01, qf1, S0);
        f32x16 S1 = MFMA32(kf10, qf0, z16);
        S1 = MFMA32(kf11, qf1, S1);
        // ---- exp + pack tile0 (keys 0..31 of step) ----
        float p0[16];
        #pragma unroll
        for (int i = 0; i < 16; ++i) {
            p0[i] = __builtin_amdgcn_exp2f(S0[i]);
            lsum += p0[i];
        }
        bf16x8 fA = pack8(p0);
        bf16x8 fB = pack8(p0 + 8);
        // ---- PV kc=0,1 ----
        {
            bf16x8 v0 = *reinterpret_cast<const bf16x8*>(Vc + 0 * 512 + gslot8);
            bf16x8 v1 = *reinterpret_cast<const bf16x8*>(Vc + 1 * 512 + gslot8);
            bf16x8 v2 = *reinterpret_cast<const bf16x8*>(Vc + 2 * 512 + gslot8);
            bf16x8 v3 = *reinterpret_cast<const bf16x8*>(Vc + 3 * 512 + gslot8);
            O0 = MFMA32(v0, fA, O0);
            O1 = MFMA32(v1, fA, O1);
            O2 = MFMA32(v2, fA, O2);
            O3 = MFMA32(v3, fA, O3);
            bf16x8 v4 = *reinterpret_cast<const bf16x8*>(Vc + 4 * 512 + gslot8);
            bf16x8 v5 = *reinterpret_cast<const bf16x8*>(Vc + 5 * 512 + gslot8);
            bf16x8 v6 = *reinterpret_cast<const bf16x8*>(Vc + 6 * 512 + gslot8);
            bf16x8 v7 = *reinterpret_cast<const bf16x8*>(Vc + 7 * 512 + gslot8);
            O0 = MFMA32(v4, fB, O0);
            O1 = MFMA32(v5, fB, O1);
            O2 = MFMA32(v6, fB, O2);
            O3 = MFMA32(v7, fB, O3);
        }
        // ---- exp + pack tile1 (keys 32..63) ----
        float p1[16];
        #pragma unroll
        for (int i = 0; i < 16; ++i) {
            p1[i] = __builtin_amdgcn_exp2f(S1[i]);
            lsum += p1[i];
        }
        bf16x8 fC = pack8(p1);
        bf16x8 fD = pack8(p1 + 8);
        // ---- PV kc=2,3 ----
        {
            bf16x8 v0 = *reinterpret_cast<const bf16x8*>(Vc + 8 * 512 + gslot8);
            bf16x8 v1 = *reinterpret_cast<const bf16x8*>(Vc + 9 * 512 + gslot8);
            bf16x8 v2 = *reinterpret_cast<const bf16x8*>(Vc + 10 * 512 + gslot8);
            bf16x8 v3 = *reinterpret_cast<const bf16x8*>(Vc + 11 * 512 + gslot8);
            O0 = MFMA32(v0, fC, O0);
            O1 = MFMA32(v1, fC, O1);
            O2 = MFMA32(v2, fC, O2);
            O3 = MFMA32(v3, fC, O3);
            bf16x8 v4 = *reinterpret_cast<const bf16x8*>(Vc + 12 * 512 + gslot8);
            bf16x8 v5 = *reinterpret_cast<const bf16x8*>(Vc + 13 * 512 + gslot8);
            bf16x8 v6 = *reinterpret_cast<const bf16x8*>(Vc + 14 * 512 + gslot8);
            bf16x8 v7 = *reinterpret_cast<const bf16x8*>(Vc + 15 * 512 + gslot8);
            O0 = MFMA32(v4, fD, O0);
            O1 = MFMA32(v5, fD, O1);
            O2 = MFMA32(v6, fD, O2);
            O3 = MFMA32(v7, fD, O3);
        }
        __syncthreads();
    }

    // row-sum completion: hi halves hold disjoint key subsets for q = la
    lsum += __shfl_xor(lsum, 32, 64);
    float linv = 1.0f / lsum;
    float gm = gamma[0];
    const float* xb = x + (size_t)b * 256 * 4096;
    float* ob = out + (size_t)b * 256 * 4096;
    int m = m0 + w * 32 + la;
    #pragma unroll
    for (int r = 0; r < 16; ++r) {
        int crow = (r & 3) + 8 * (r >> 2) + 4 * hi;
        size_t i0 = (size_t)(ch0 + crow) * 4096 + m;
        ob[i0]             = gm * (O0[r] * linv) + xb[i0];
        ob[i0 + 32 * 4096] = gm * (O1[r] * linv) + xb[i0 + 32 * 4096];
        ob[i0 + 64 * 4096] = gm * (O2[r] * linv) + xb[i0 + 64 * 4096];
        ob[i0 + 96 * 4096] = gm * (O3[r] * linv) + xb[i0 + 96 * 4096];
    }
}

// ---------------------------------------------------------------------------
// fp32 I/O. Internal bf16. Workspace: qt 2 + kt 2 + vt 16 = 20 MiB.
// xT (bf16, 16 MiB) staged inside fp32 d_out (32 MiB); dead before k_flash.
// ---------------------------------------------------------------------------
extern "C" void kernel_launch(void* const* d_in, const int* in_sizes, int n_in,
                              void* d_out, int out_size, void* d_ws, size_t ws_size,
                              hipStream_t stream) {
    const float* x     = (const float*)d_in[0];
    const float* Wq    = (const float*)d_in[1];
    const float* bq    = (const float*)d_in[2];
    const float* Wk    = (const float*)d_in[3];
    const float* bk    = (const float*)d_in[4];
    const float* Wv    = (const float*)d_in[5];
    const float* bv    = (const float*)d_in[6];
    const float* gamma = (const float*)d_in[7];
    float* out = (float*)d_out;

    char* ws = (char*)d_ws;
    u16* xT = (u16*)d_out;                        // 16 MiB bf16 scratch in fp32 d_out
    u16* qt = (u16*)ws;                           //  2 MiB [B,N,32]
    u16* kt = (u16*)(ws + 2097152);               //  2 MiB [B,N,32]
    u16* vt = (u16*)(ws + 2 * 2097152);           // 16 MiB [B,nt,ch,16]

    k_transpose<<<2048, 256, 0, stream>>>(x, xT);
    k_proj<<<512, 256, 0, stream>>>(xT, Wq, bq, Wk, bk, Wv, bv, qt, kt, vt);
    k_flash<<<512, 256, 0, stream>>>(qt, kt, vt, x, gamma, out);
}

// Round 4
// 199.928 us; speedup vs baseline: 1.8534x; 1.0221x over previous
//
#include <hip/hip_runtime.h>
#include <stdint.h>

typedef unsigned short u16;
typedef unsigned int u32;
typedef __bf16 bf16_t;
typedef __bf16 bf16x4 __attribute__((ext_vector_type(4)));
typedef __bf16 bf16x8 __attribute__((ext_vector_type(8)));
typedef float f32x4 __attribute__((ext_vector_type(4)));
typedef float f32x16 __attribute__((ext_vector_type(16)));

#define LOG2E 1.4426950408889634f
#define MFMA32(a, b, c) __builtin_amdgcn_mfma_f32_32x32x16_bf16(a, b, c, 0, 0, 0)

__device__ __forceinline__ u16 f2bf(float f) {
    union { float f; unsigned int u; } v; v.f = f;
    unsigned int r = v.u + 0x7fffu + ((v.u >> 16) & 1u);
    return (u16)(r >> 16);
}

__device__ __forceinline__ bf16x8 ld8f_bf(const float* __restrict__ p) {
    float4 a = *reinterpret_cast<const float4*>(p);
    float4 b = *reinterpret_cast<const float4*>(p + 4);
    bf16x8 r;
    r[0] = (bf16_t)a.x; r[1] = (bf16_t)a.y; r[2] = (bf16_t)a.z; r[3] = (bf16_t)a.w;
    r[4] = (bf16_t)b.x; r[5] = (bf16_t)b.y; r[6] = (bf16_t)b.z; r[7] = (bf16_t)b.w;
    return r;
}

__device__ __forceinline__ u32 cvt_pk_bf16(float a, float b) {
    u32 r;
    asm("v_cvt_pk_bf16_f32 %0, %1, %2" : "=v"(r) : "v"(a), "v"(b));
    return r;
}

__device__ __forceinline__ void plane32_swap(u32& a, u32& b) {
    asm("v_permlane32_swap_b32 %0, %1" : "+v"(a), "+v"(b));
}

// Build PV B-operand fragment (16 keys) from 8 consecutive QK C-regs.
__device__ __forceinline__ bf16x8 pack8(const float* p) {
    u32 c0 = cvt_pk_bf16(p[0], p[1]);
    u32 c1 = cvt_pk_bf16(p[2], p[3]);
    u32 c2 = cvt_pk_bf16(p[4], p[5]);
    u32 c3 = cvt_pk_bf16(p[6], p[7]);
    plane32_swap(c0, c2);
    plane32_swap(c1, c3);
    union { u32 u[4]; bf16x8 v; } f;
    f.u[0] = c0; f.u[1] = c1; f.u[2] = c2; f.u[3] = c3;
    return f.v;
}

// async global->LDS, 16B per lane; LDS dest wave-uniform base + lane*16
__device__ __forceinline__ void g2lds16(const u16* g, u16* l) {
    __builtin_amdgcn_global_load_lds(
        (const __attribute__((address_space(1))) unsigned int*)g,
        (__attribute__((address_space(3))) unsigned int*)l, 16, 0, 0);
}

// ---------------------------------------------------------------------------
// Kernel 1: x[B,C,N] fp32 -> xT[B,N,C] bf16, PRE-SWIZZLED per 16B granule:
// row n, granule g stored at granule slot g^(n&7)  (so k_proj can stage Xs
// with linear global_load_lds). Blocks >= 2048 convert weights to bf16:
// wqkb = [64 rows (Wq||Wk)][32 granules swizzled g^(n&7)]
// wvb  = 8 slices x 1024 granules, slot d holds Wv[d>>2][slice*32+((d&3)^((d>>2)&3))*8..+8]
// ---------------------------------------------------------------------------
__global__ __launch_bounds__(256) void k_transpose(
    const float* __restrict__ x,
    const float* __restrict__ Wq, const float* __restrict__ Wk,
    const float* __restrict__ Wv,
    u16* __restrict__ xT, u16* __restrict__ wqkb, u16* __restrict__ wvb) {
    int blk = blockIdx.x;
    int t = threadIdx.x;
    if (blk >= 2048) {
        if (blk == 2048) {          // Wq||Wk -> wqkb (2048 granules)
            for (int j = 0; j < 8; ++j) {
                int fg = j * 256 + t;
                int n = fg >> 5, g = fg & 31;
                const float* src = (n < 32) ? (Wq + (size_t)n * 256 + g * 8)
                                            : (Wk + (size_t)(n - 32) * 256 + g * 8);
                *reinterpret_cast<bf16x8*>(wqkb + n * 256 + ((g ^ (n & 7)) << 3)) =
                    ld8f_bf(src);
            }
        } else {                    // Wv -> wvb (8192 granules, blocks 2049..2052)
            int base = (blk - 2049) * 2048;
            for (int j = 0; j < 8; ++j) {
                int fg = base + j * 256 + t;
                int slice = fg >> 10, d = fg & 1023;
                int co = d >> 2, g2 = (d & 3) ^ (co & 3);
                *reinterpret_cast<bf16x8*>(wvb + fg * 8) =
                    ld8f_bf(Wv + (size_t)co * 256 + slice * 32 + g2 * 8);
            }
        }
        return;
    }
    __shared__ u16 tile[64][68];
    int b = blk >> 8;
    int r = blk & 255;
    int c0 = (r & 3) * 64;
    int n0 = (r >> 2) * 64;
    const float* xb = x + (size_t)b * 256 * 4096;
    u16* xTb = xT + (size_t)b * 4096 * 256;
    int lc = t >> 4;
    int l4 = (t & 15) * 4;
    #pragma unroll
    for (int p = 0; p < 4; ++p) {
        int c = lc + p * 16;
        float4 v = *reinterpret_cast<const float4*>(xb + (size_t)(c0 + c) * 4096 + n0 + l4);
        tile[c][l4 + 0] = f2bf(v.x); tile[c][l4 + 1] = f2bf(v.y);
        tile[c][l4 + 2] = f2bf(v.z); tile[c][l4 + 3] = f2bf(v.w);
    }
    __syncthreads();
    #pragma unroll
    for (int p = 0; p < 4; ++p) {
        int n = lc + p * 16;
        ushort4 v;
        v.x = tile[l4 + 0][n]; v.y = tile[l4 + 1][n];
        v.z = tile[l4 + 2][n]; v.w = tile[l4 + 3][n];
        int gslot = ((c0 + l4) >> 3) ^ ((n0 + n) & 7);
        *reinterpret_cast<ushort4*>(
            xTb + (size_t)(n0 + n) * 256 + (gslot << 3) + (l4 & 7)) = v;
    }
}

// ---------------------------------------------------------------------------
// Kernel 2: fused q/k/v projection. All LDS staging is now linear
// global_load_lds from pre-swizzled xT / wqkb / wvb (zero cvt VALU, zero
// ds_writes). Fragment reads identical to v6 (LDS contents bit-identical).
// q pre-scaled by LOG2E. V written in vt[b][n>>4][ch][n&15].
// ---------------------------------------------------------------------------
__global__ __launch_bounds__(256, 2) void k_proj(
    const u16* __restrict__ xT, const u16* __restrict__ wqkb,
    const u16* __restrict__ wvb,
    const float* __restrict__ bq, const float* __restrict__ bk,
    const float* __restrict__ bv,
    u16* __restrict__ qt, u16* __restrict__ kt, u16* __restrict__ vt) {
    __shared__ u16 Xs[64 * 256];
    __shared__ u16 Ws[64 * 256];
    __shared__ u16 Wvs[256 * 32];
    int blk = blockIdx.x;
    int b = blk & 7;
    int n0 = (blk >> 3) * 64;
    int t = threadIdx.x;
    int w = t >> 6;
    int lane = t & 63;
    int lo = lane & 15;
    int q = lane >> 4;
    const u16* xTb = xT + (size_t)b * 4096 * 256;

    // ---- stage Xs and Ws: linear async copies ----
    #pragma unroll
    for (int p = 0; p < 8; ++p) {
        g2lds16(xTb + (size_t)n0 * 256 + (p * 256 + t) * 8, &Xs[(p * 256 + w * 64) * 8]);
        g2lds16(wqkb + (p * 256 + t) * 8, &Ws[(p * 256 + w * 64) * 8]);
    }

    f32x4 accqk[4] = {};
    f32x4 accv[16];
    #pragma unroll
    for (int i = 0; i < 16; ++i) accv[i] = f32x4{0.f, 0.f, 0.f, 0.f};

    int rowA = w * 16 + lo;
    int cw = w * 64;
    for (int c0 = 0; c0 < 256; c0 += 32) {
        __syncthreads();   // prev Wvs reads done (also covers initial Xs/Ws staging)
        #pragma unroll
        for (int p = 0; p < 4; ++p) {
            g2lds16(wvb + (size_t)(c0 >> 5) * 8192 + (p * 256 + t) * 8,
                    &Wvs[(p * 256 + w * 64) * 8]);
        }
        __syncthreads();   // Wvs staged (drains vmcnt)

        int K = c0 >> 3;
        bf16x8 a = *reinterpret_cast<const bf16x8*>(
            &Xs[(rowA * 32 + ((K + q) ^ (lo & 7))) * 8]);
        #pragma unroll
        for (int ot = 0; ot < 4; ++ot) {
            bf16x8 bb = *reinterpret_cast<const bf16x8*>(
                &Ws[((ot * 16 + lo) * 32 + ((K + q) ^ (lo & 7))) * 8]);
            accqk[ot] = __builtin_amdgcn_mfma_f32_16x16x32_bf16(a, bb, accqk[ot], 0, 0, 0);
        }
        bf16x8 xbf[4];
        #pragma unroll
        for (int nt = 0; nt < 4; ++nt)
            xbf[nt] = *reinterpret_cast<const bf16x8*>(
                &Xs[((nt * 16 + lo) * 32 + ((K + q) ^ (lo & 7))) * 8]);
        #pragma unroll
        for (int ct = 0; ct < 4; ++ct) {
            int co = cw + ct * 16 + lo;
            bf16x8 av = *reinterpret_cast<const bf16x8*>(
                &Wvs[(co * 4 + (q ^ (co & 3))) * 8]);
            #pragma unroll
            for (int nt = 0; nt < 4; ++nt)
                accv[ct * 4 + nt] = __builtin_amdgcn_mfma_f32_16x16x32_bf16(
                    av, xbf[nt], accv[ct * 4 + nt], 0, 0, 0);
        }
    }
    #pragma unroll
    for (int ot = 0; ot < 4; ++ot) {
        float bias = (ot < 2) ? bq[ot * 16 + lo] : bk[(ot - 2) * 16 + lo];
        #pragma unroll
        for (int r = 0; r < 4; ++r) {
            int n = n0 + w * 16 + q * 4 + r;
            float val = accqk[ot][r] + bias;
            if (ot < 2) qt[((size_t)b * 4096 + n) * 32 + ot * 16 + lo] = f2bf(val * LOG2E);
            else        kt[((size_t)b * 4096 + n) * 32 + (ot - 2) * 16 + lo] = f2bf(val);
        }
    }
    #pragma unroll
    for (int ct = 0; ct < 4; ++ct) {
        #pragma unroll
        for (int nt = 0; nt < 4; ++nt) {
            int nt_g = (n0 >> 4) + nt;
            #pragma unroll
            for (int r = 0; r < 4; ++r) {
                int co = cw + ct * 16 + q * 4 + r;
                float val = accv[ct * 4 + nt][r] + bv[co];
                vt[(((size_t)b * 256 + nt_g) * 256 + co) * 16 + lo] = f2bf(val);
            }
        }
    }
}

// ---------------------------------------------------------------------------
// Kernel 3 (v7): cross-step pipelined flash attention.
// Per iter s: issue K(s+2)->regs, g2lds V(s+1), QK(s+1)+exp(s+1) [VALU]
// overlapped with PV(s) [LDS+MFMA], one barrier. K in registers (no LDS),
// unroll-x2 keeps all rolling state statically named.
// ---------------------------------------------------------------------------
#define FLASH_PV_HALF1(FC0, FC1, Vc_)                                          \
    {                                                                          \
        bf16x8 v0_ = *reinterpret_cast<const bf16x8*>(Vc_ + gslot8);           \
        bf16x8 v1_ = *reinterpret_cast<const bf16x8*>(Vc_ + 512 + gslot8);     \
        bf16x8 v2_ = *reinterpret_cast<const bf16x8*>(Vc_ + 1024 + gslot8);    \
        bf16x8 v3_ = *reinterpret_cast<const bf16x8*>(Vc_ + 1536 + gslot8);    \
        O0 = MFMA32(v0_, FC0, O0); O1 = MFMA32(v1_, FC0, O1);                  \
        O2 = MFMA32(v2_, FC0, O2); O3 = MFMA32(v3_, FC0, O3);                  \
        bf16x8 v4_ = *reinterpret_cast<const bf16x8*>(Vc_ + 2048 + gslot8);    \
        bf16x8 v5_ = *reinterpret_cast<const bf16x8*>(Vc_ + 2560 + gslot8);    \
        bf16x8 v6_ = *reinterpret_cast<const bf16x8*>(Vc_ + 3072 + gslot8);    \
        bf16x8 v7_ = *reinterpret_cast<const bf16x8*>(Vc_ + 3584 + gslot8);    \
        O0 = MFMA32(v4_, FC1, O0); O1 = MFMA32(v5_, FC1, O1);                  \
        O2 = MFMA32(v6_, FC1, O2); O3 = MFMA32(v7_, FC1, O3);                  \
    }

#define FLASH_PV_HALF2(FC2, FC3, Vc_)                                          \
    {                                                                          \
        bf16x8 v0_ = *reinterpret_cast<const bf16x8*>(Vc_ + 4096 + gslot8);    \
        bf16x8 v1_ = *reinterpret_cast<const bf16x8*>(Vc_ + 4608 + gslot8);    \
        bf16x8 v2_ = *reinterpret_cast<const bf16x8*>(Vc_ + 5120 + gslot8);    \
        bf16x8 v3_ = *reinterpret_cast<const bf16x8*>(Vc_ + 5632 + gslot8);    \
        O0 = MFMA32(v0_, FC2, O0); O1 = MFMA32(v1_, FC2, O1);                  \
        O2 = MFMA32(v2_, FC2, O2); O3 = MFMA32(v3_, FC2, O3);                  \
        bf16x8 v4_ = *reinterpret_cast<const bf16x8*>(Vc_ + 6144 + gslot8);    \
        bf16x8 v5_ = *reinterpret_cast<const bf16x8*>(Vc_ + 6656 + gslot8);    \
        bf16x8 v6_ = *reinterpret_cast<const bf16x8*>(Vc_ + 7168 + gslot8);    \
        bf16x8 v7_ = *reinterpret_cast<const bf16x8*>(Vc_ + 7680 + gslot8);    \
        O0 = MFMA32(v4_, FC3, O0); O1 = MFMA32(v5_, FC3, O1);                  \
        O2 = MFMA32(v6_, FC3, O2); O3 = MFMA32(v7_, FC3, O3);                  \
    }

#define FLASH_ITER(S_, KC0, KC1, KC2, KC3, KN0, KN1, KN2, KN3,                 \
                   FC0, FC1, FC2, FC3, FN0, FN1, FN2, FN3, VDN)                \
    {                                                                          \
        const int s_ = (S_);                                                   \
        const u16* kp_ = kbase + (size_t)(((s_ + 2) & 63) * 2048);             \
        KN0 = *reinterpret_cast<const bf16x8*>(kp_);                           \
        KN1 = *reinterpret_cast<const bf16x8*>(kp_ + 16);                      \
        KN2 = *reinterpret_cast<const bf16x8*>(kp_ + 1024);                    \
        KN3 = *reinterpret_cast<const bf16x8*>(kp_ + 1040);                    \
        const u16* vs_ = vstage + (size_t)(s_ + 1) * 16384;                    \
        g2lds16(vs_,        VDN);                                              \
        g2lds16(vs_ + 512,  VDN + 512);                                        \
        g2lds16(vs_ + 1024, VDN + 1024);                                       \
        g2lds16(vs_ + 1536, VDN + 1536);                                       \
        f32x16 S0_ = MFMA32(KC0, qf0, z16); S0_ = MFMA32(KC1, qf1, S0_);       \
        f32x16 S1_ = MFMA32(KC2, qf0, z16); S1_ = MFMA32(KC3, qf1, S1_);       \
        const u16* Vc_ = Vs[s_ & 1];                                           \
        float p0_[16];                                                         \
        _Pragma("unroll")                                                      \
        for (int i_ = 0; i_ < 16; ++i_) {                                      \
            p0_[i_] = __builtin_amdgcn_exp2f(S0_[i_]); lsum += p0_[i_];        \
        }                                                                      \
        FN0 = pack8(p0_); FN1 = pack8(p0_ + 8);                                \
        FLASH_PV_HALF1(FC0, FC1, Vc_)                                          \
        float p1_[16];                                                         \
        _Pragma("unroll")                                                      \
        for (int i_ = 0; i_ < 16; ++i_) {                                      \
            p1_[i_] = __builtin_amdgcn_exp2f(S1_[i_]); lsum += p1_[i_];        \
        }                                                                      \
        FN2 = pack8(p1_); FN3 = pack8(p1_ + 8);                                \
        FLASH_PV_HALF2(FC2, FC3, Vc_)                                          \
        __syncthreads();                                                       \
    }

__global__ __launch_bounds__(256, 2) void k_flash(
    const u16* __restrict__ qt, const u16* __restrict__ kt,
    const u16* __restrict__ vt, const float* __restrict__ x,
    const float* __restrict__ gamma, float* __restrict__ out) {
    __shared__ u16 Vs[2][8192];   // 16 chunks (kc*4+cg) x 512 u16 per buffer
    int blk = blockIdx.x;
    int b = blk & 7;
    int rest = blk >> 3;
    int m0 = (rest & 31) * 128;
    int ch0 = (rest >> 5) * 128;
    int t = threadIdx.x;
    int w = t >> 6;
    int lane = t & 63;
    int la = lane & 31;
    int hi = lane >> 5;

    const u16* qtb = qt + (size_t)b * 4096 * 32;
    const u16* ktb = kt + (size_t)b * 4096 * 32;
    const u16* vtb = vt + (size_t)b * 256 * 256 * 16;

    int qw0 = m0 + w * 32;
    bf16x8 qf0 = *reinterpret_cast<const bf16x8*>(qtb + (size_t)(qw0 + la) * 32 + hi * 8);
    bf16x8 qf1 = *reinterpret_cast<const bf16x8*>(qtb + (size_t)(qw0 + la) * 32 + 16 + hi * 8);

    const u16* kbase = ktb + (size_t)la * 32 + hi * 8;

    int g = la * 2 + hi;
    int gslot8 = (g ^ (g >> 3)) * 8;   // read-slot swizzle (involution)
    int sg = lane ^ (lane >> 3);       // pre-swizzled staging source granule
    const u16* vstage = vtb + ((size_t)(w * 256) + ch0) * 16 + sg * 8;
    u16* vd0 = &Vs[0][w * 2048];
    u16* vd1 = &Vs[1][w * 2048];

    f32x16 O0 = {}, O1 = {}, O2 = {}, O3 = {};
    const f32x16 z16 = {};
    float lsum = 0.f;

    bf16x8 kA0, kA1, kA2, kA3, kB0, kB1, kB2, kB3;
    bf16x8 fA0, fA1, fA2, fA3, fB0, fB1, fB2, fB3;

    // ---- prologue: K(0)->kA, stage V(0), K(1)->kB, frags(0)->fA ----
    kA0 = *reinterpret_cast<const bf16x8*>(kbase);
    kA1 = *reinterpret_cast<const bf16x8*>(kbase + 16);
    kA2 = *reinterpret_cast<const bf16x8*>(kbase + 1024);
    kA3 = *reinterpret_cast<const bf16x8*>(kbase + 1040);
    g2lds16(vstage,        vd0);
    g2lds16(vstage + 512,  vd0 + 512);
    g2lds16(vstage + 1024, vd0 + 1024);
    g2lds16(vstage + 1536, vd0 + 1536);
    kB0 = *reinterpret_cast<const bf16x8*>(kbase + 2048);
    kB1 = *reinterpret_cast<const bf16x8*>(kbase + 2064);
    kB2 = *reinterpret_cast<const bf16x8*>(kbase + 3072);
    kB3 = *reinterpret_cast<const bf16x8*>(kbase + 3088);
    {
        f32x16 S0 = MFMA32(kA0, qf0, z16); S0 = MFMA32(kA1, qf1, S0);
        f32x16 S1 = MFMA32(kA2, qf0, z16); S1 = MFMA32(kA3, qf1, S1);
        float p0[16], p1[16];
        #pragma unroll
        for (int i = 0; i < 16; ++i) { p0[i] = __builtin_amdgcn_exp2f(S0[i]); lsum += p0[i]; }
        fA0 = pack8(p0); fA1 = pack8(p0 + 8);
        #pragma unroll
        for (int i = 0; i < 16; ++i) { p1[i] = __builtin_amdgcn_exp2f(S1[i]); lsum += p1[i]; }
        fA2 = pack8(p1); fA3 = pack8(p1 + 8);
    }
    __syncthreads();   // V(0) staged

    // ---- main loop: s = 0..61 (31 unrolled pairs) ----
    for (int ss = 0; ss < 31; ++ss) {
        int s0 = ss * 2;
        FLASH_ITER(s0,     kB0, kB1, kB2, kB3, kA0, kA1, kA2, kA3,
                           fA0, fA1, fA2, fA3, fB0, fB1, fB2, fB3, vd1)
        FLASH_ITER(s0 + 1, kA0, kA1, kA2, kA3, kB0, kB1, kB2, kB3,
                           fB0, fB1, fB2, fB3, fA0, fA1, fA2, fA3, vd0)
    }
    // ---- s = 62: full iter (produces frags(63), stages V(63)) ----
    FLASH_ITER(62, kB0, kB1, kB2, kB3, kA0, kA1, kA2, kA3,
                   fA0, fA1, fA2, fA3, fB0, fB1, fB2, fB3, vd1)
    // ---- s = 63: PV only ----
    {
        const u16* Vc_ = Vs[1];
        FLASH_PV_HALF1(fB0, fB1, Vc_)
        FLASH_PV_HALF2(fB2, fB3, Vc_)
    }

    // row-sum completion: hi halves hold disjoint key subsets for q = la
    lsum += __shfl_xor(lsum, 32, 64);
    float linv = 1.0f / lsum;
    float gm = gamma[0];
    const float* xb = x + (size_t)b * 256 * 4096;
    float* ob = out + (size_t)b * 256 * 4096;
    int m = m0 + w * 32 + la;
    #pragma unroll
    for (int r = 0; r < 16; ++r) {
        int crow = (r & 3) + 8 * (r >> 2) + 4 * hi;
        size_t i0 = (size_t)(ch0 + crow) * 4096 + m;
        ob[i0]             = gm * (O0[r] * linv) + xb[i0];
        ob[i0 + 32 * 4096] = gm * (O1[r] * linv) + xb[i0 + 32 * 4096];
        ob[i0 + 64 * 4096] = gm * (O2[r] * linv) + xb[i0 + 64 * 4096];
        ob[i0 + 96 * 4096] = gm * (O3[r] * linv) + xb[i0 + 96 * 4096];
    }
}

// ---------------------------------------------------------------------------
// fp32 I/O. Internal bf16. Workspace: qt 2 + kt 2 + vt 16 = 20 MiB.
// d_out (32 MiB): xT bf16 16 MiB + wqkb 32 KiB + wvb 128 KiB (all dead
// before k_flash writes out).
// ---------------------------------------------------------------------------
extern "C" void kernel_launch(void* const* d_in, const int* in_sizes, int n_in,
                              void* d_out, int out_size, void* d_ws, size_t ws_size,
                              hipStream_t stream) {
    const float* x     = (const float*)d_in[0];
    const float* Wq    = (const float*)d_in[1];
    const float* bq    = (const float*)d_in[2];
    const float* Wk    = (const float*)d_in[3];
    const float* bk    = (const float*)d_in[4];
    const float* Wv    = (const float*)d_in[5];
    const float* bv    = (const float*)d_in[6];
    const float* gamma = (const float*)d_in[7];
    float* out = (float*)d_out;

    char* ws = (char*)d_ws;
    u16* xT   = (u16*)d_out;                      // 16 MiB bf16 scratch in d_out
    u16* wqkb = (u16*)d_out + 8388608;            // 32 KiB
    u16* wvb  = (u16*)d_out + 8388608 + 16384;    // 128 KiB
    u16* qt = (u16*)ws;                           //  2 MiB [B,N,32]
    u16* kt = (u16*)(ws + 2097152);               //  2 MiB [B,N,32]
    u16* vt = (u16*)(ws + 2 * 2097152);           // 16 MiB [B,nt,ch,16]

    k_transpose<<<2053, 256, 0, stream>>>(x, Wq, Wk, Wv, xT, wqkb, wvb);
    k_proj<<<512, 256, 0, stream>>>(xT, wqkb, wvb, bq, bk, bv, qt, kt, vt);
    k_flash<<<512, 256, 0, stream>>>(qt, kt, vt, x, gamma, out);
}